// Round 2
// baseline (866.217 us; speedup 1.0000x reference)
//
#include <hip/hip_runtime.h>
#include <cstdint>
#include <cfloat>

// Problem constants (reference: B=4096, D=1024, C=100, K=(4,8,16))
#define B_N   4096
#define D_N   1024
#define BASE1 400      // global col base of group1
#define BASE2 1200     // global col base of group2
#define NTOT  2800
#define NPIECE 24      // col pieces of 128: g0: 0..3, g1: 4..10, g2: 11..23
#define XS_LD 132      // LDS row stride (floats): bank = (k*4 + row) % 32

// ---------------------------------------------------------------------------
// Kernel 1: squared norms of all 2800 prototype rows. One wave (64 lanes)/row.
// ---------------------------------------------------------------------------
__global__ __launch_bounds__(256) void norms_kernel(
    const float* __restrict__ P0, const float* __restrict__ P1,
    const float* __restrict__ P2, float* __restrict__ f2) {
  int row  = blockIdx.x * 4 + (threadIdx.x >> 6);
  int lane = threadIdx.x & 63;
  if (row >= NTOT) return;
  const float* src;
  if (row < BASE1)      src = P0 + (size_t)row * D_N;
  else if (row < BASE2) src = P1 + (size_t)(row - BASE1) * D_N;
  else                  src = P2 + (size_t)(row - BASE2) * D_N;
  float s = 0.f;
  for (int k = 0; k < D_N; k += 256) {
    float4 v = *(const float4*)&src[k + lane * 4];
    s += v.x * v.x + v.y * v.y + v.z * v.z + v.w * v.w;
  }
#pragma unroll
  for (int off = 32; off >= 1; off >>= 1) s += __shfl_xor(s, off, 64);
  if (lane == 0) f2[row] = s;
}

// ---------------------------------------------------------------------------
// Kernel 2: tiled fp32 GEMM (x @ P^T) with argmin epilogue on f2 - 2*dot.
// Block = 128 b-rows x 128 cols (one piece). 256 threads, 8x8 register tile,
// BK=32 LDS staging, [k][row] transposed layout, stride 132.
// Writes per-(row,piece) partial (minval, argidx).
// ---------------------------------------------------------------------------
__global__ __launch_bounds__(256, 3) void argmin_kernel(
    const float* __restrict__ x, const float* __restrict__ P0,
    const float* __restrict__ P1, const float* __restrict__ P2,
    const float* __restrict__ f2, float* __restrict__ pval,
    int* __restrict__ pidx) {
  __shared__ float sh[2 * 32 * XS_LD];   // xs | ps, 33.8 KB
  float* xs = sh;
  float* ps = sh + 32 * XS_LD;

  const int tid = threadIdx.x;
  const int tx = tid & 15, ty = tid >> 4;
  const int b0 = blockIdx.x * 128;
  const int piece = blockIdx.y;

  const float* Pg; int gbase, jend, jstart;
  if (piece < 4)       { Pg = P0; gbase = 0;     jend = 400;  jstart = piece * 128; }
  else if (piece < 11) { Pg = P1; gbase = BASE1; jend = 1200; jstart = 400 + (piece - 4) * 128; }
  else                 { Pg = P2; gbase = BASE2; jend = 2800; jstart = 1200 + (piece - 11) * 128; }

  // staging mapping: thread -> (row srow 0..127, k-half skh 0..1)
  const int srow = tid >> 1;
  const int skh  = (tid & 1) * 16;
  const int pj   = jstart + srow;
  const bool pvalid = pj < jend;
  const float* psrc = Pg + (size_t)(pj - gbase) * D_N;   // deref only if pvalid
  const float* xsrc = x + (size_t)(b0 + srow) * D_N;

  float acc[8][8];
#pragma unroll
  for (int i = 0; i < 8; ++i)
#pragma unroll
    for (int j = 0; j < 8; ++j) acc[i][j] = 0.f;

  for (int k0 = 0; k0 < D_N; k0 += 32) {
    __syncthreads();   // previous iter's LDS reads complete before overwrite
#pragma unroll
    for (int q = 0; q < 4; ++q) {
      const int kk = skh + q * 4;
      float4 v = *(const float4*)&xsrc[k0 + kk];
      xs[(kk + 0) * XS_LD + srow] = v.x;
      xs[(kk + 1) * XS_LD + srow] = v.y;
      xs[(kk + 2) * XS_LD + srow] = v.z;
      xs[(kk + 3) * XS_LD + srow] = v.w;
      float4 w = make_float4(0.f, 0.f, 0.f, 0.f);
      if (pvalid) w = *(const float4*)&psrc[k0 + kk];
      ps[(kk + 0) * XS_LD + srow] = w.x;
      ps[(kk + 1) * XS_LD + srow] = w.y;
      ps[(kk + 2) * XS_LD + srow] = w.z;
      ps[(kk + 3) * XS_LD + srow] = w.w;
    }
    __syncthreads();
#pragma unroll 8
    for (int k = 0; k < 32; ++k) {
      // a: rows {ty*4+i, 64+ty*4+i}; broadcast reads (4 distinct addrs/wave)
      float4 a0 = *(const float4*)&xs[k * XS_LD + ty * 4];
      float4 a1 = *(const float4*)&xs[k * XS_LD + 64 + ty * 4];
      // b: cols {tx*4+c, 64+tx*4+c}; 2-way bank alias (free)
      float4 p0 = *(const float4*)&ps[k * XS_LD + tx * 4];
      float4 p1 = *(const float4*)&ps[k * XS_LD + 64 + tx * 4];
      float a[8] = {a0.x, a0.y, a0.z, a0.w, a1.x, a1.y, a1.z, a1.w};
      float b[8] = {p0.x, p0.y, p0.z, p0.w, p1.x, p1.y, p1.z, p1.w};
#pragma unroll
      for (int i = 0; i < 8; ++i)
#pragma unroll
        for (int j = 0; j < 8; ++j)
          acc[i][j] = fmaf(a[i], b[j], acc[i][j]);
    }
  }

  // epilogue: score = f2[j] - 2*dot; per-thread best over 8 cols, then
  // cross-tx reduce per row via LDS (reuse sh after barrier).
  float* rv = sh;                      // 128*16 floats
  int*   ri = (int*)(sh + 32 * XS_LD); // 128*16 ints
  __syncthreads();
#pragma unroll
  for (int half = 0; half < 2; ++half) {
#pragma unroll
    for (int i = 0; i < 4; ++i) {
      const int lr = half * 64 + ty * 4 + i;   // local row 0..127
      float bv = FLT_MAX; int bi = 0;
#pragma unroll
      for (int h2 = 0; h2 < 2; ++h2) {
#pragma unroll
        for (int c = 0; c < 4; ++c) {
          const int j = jstart + h2 * 64 + tx * 4 + c;   // ascending within thread
          const float fj = (j < jend) ? f2[j] : FLT_MAX;
          const float s = fmaf(-2.f, acc[half * 4 + i][h2 * 4 + c], fj);
          if (s < bv) { bv = s; bi = j; }
        }
      }
      rv[lr * 16 + tx] = bv;
      ri[lr * 16 + tx] = bi;
    }
  }
  __syncthreads();
  if (tid < 128) {
    float v = rv[tid * 16]; int ix = ri[tid * 16];
#pragma unroll
    for (int t = 1; t < 16; ++t) {
      const float vv = rv[tid * 16 + t]; const int ii = ri[tid * 16 + t];
      if (vv < v || (vv == v && ii < ix)) { v = vv; ix = ii; }
    }
    pval[(size_t)(b0 + tid) * NPIECE + piece] = v;
    pidx[(size_t)(b0 + tid) * NPIECE + piece] = ix;
  }
}

// ---------------------------------------------------------------------------
// Kernel 3: combine per-piece partials into per-group argmin; emit cls floats.
// ---------------------------------------------------------------------------
__global__ __launch_bounds__(256) void combine_kernel(
    const float* __restrict__ pval, const int* __restrict__ pidx,
    int* __restrict__ fidx, float* __restrict__ out) {
  int b = blockIdx.x * 256 + threadIdx.x;
  if (b >= B_N) return;
  const float* pv = pval + (size_t)b * NPIECE;
  const int*   pi = pidx + (size_t)b * NPIECE;
  int lo[3] = {0, 4, 11}, hi[3] = {4, 11, 24};
  int ix2 = 0;
#pragma unroll
  for (int g = 0; g < 3; ++g) {
    float v = pv[lo[g]]; int ix = pi[lo[g]];
    for (int c = lo[g] + 1; c < hi[g]; ++c) {
      const float vv = pv[c]; const int ii = pi[c];
      if (vv < v || (vv == v && ii < ix)) { v = vv; ix = ii; }
    }
    fidx[b * 3 + g] = ix;
    if (g == 2) ix2 = ix;
  }
  // class_indices from LAST group, as float, at tail of out
  out[(size_t)B_N * 31 * D_N + b] = (float)((ix2 - BASE2) >> 4);
}

// ---------------------------------------------------------------------------
// Kernel 4: gather rows into out. One block per output row (B*31 rows),
// 256 threads x 1 float4 each = 4 KB coalesced copy.
// ---------------------------------------------------------------------------
__global__ __launch_bounds__(256) void gather_kernel(
    const float* __restrict__ P0, const float* __restrict__ P1,
    const float* __restrict__ P2, const int* __restrict__ fidx,
    float* __restrict__ out) {
  int r = blockIdx.x;
  int b = r / 31;
  int s = r - b * 31;
  const float* src; float* dst;
  if (s < 3) {
    int gidx = fidx[b * 3 + s];
    if (s == 0)      src = P0 + (size_t)gidx * D_N;
    else if (s == 1) src = P1 + (size_t)(gidx - BASE1) * D_N;
    else             src = P2 + (size_t)(gidx - BASE2) * D_N;
    dst = out + ((size_t)b * 3 + s) * D_N;
  } else {
    int s2 = s - 3;
    const float* Pg; int row, K, g, base;
    if (s2 < 4)       { Pg = P0; row = s2;      K = 4;  g = 0; base = 0; }
    else if (s2 < 12) { Pg = P1; row = s2 - 4;  K = 8;  g = 1; base = BASE1; }
    else              { Pg = P2; row = s2 - 12; K = 16; g = 2; base = BASE2; }
    int local = fidx[b * 3 + g] - base;
    int cls   = local / K;  // K is a power of two
    src = Pg + ((size_t)cls * K + row) * D_N;
    dst = out + (size_t)B_N * 3 * D_N + ((size_t)b * 28 + s2) * D_N;
  }
  float4 v = ((const float4*)src)[threadIdx.x];
  ((float4*)dst)[threadIdx.x] = v;
}

// ---------------------------------------------------------------------------
extern "C" void kernel_launch(void* const* d_in, const int* in_sizes, int n_in,
                              void* d_out, int out_size, void* d_ws, size_t ws_size,
                              hipStream_t stream) {
  const float* x  = (const float*)d_in[0];
  const float* P0 = (const float*)d_in[1];
  const float* P1 = (const float*)d_in[2];
  const float* P2 = (const float*)d_in[3];
  float* out = (float*)d_out;

  // workspace layout (floats/ints), ~850 KB total
  float* f2   = (float*)d_ws;                    // 2816 (2800 used)
  float* pval = f2 + 2816;                       // B*24
  int*   pidx = (int*)(pval + B_N * NPIECE);     // B*24
  int*   fidx = pidx + B_N * NPIECE;             // B*3

  norms_kernel<<<700, 256, 0, stream>>>(P0, P1, P2, f2);
  argmin_kernel<<<dim3(B_N / 128, NPIECE), 256, 0, stream>>>(x, P0, P1, P2, f2, pval, pidx);
  combine_kernel<<<(B_N + 255) / 256, 256, 0, stream>>>(pval, pidx, fidx, out);
  gather_kernel<<<B_N * 31, 256, 0, stream>>>(P0, P1, P2, fidx, out);
}